// Round 6
// baseline (168.393 us; speedup 1.0000x reference)
//
#include <hip/hip_runtime.h>
#include <hip/hip_bf16.h>

// Problem constants: B=16, L=50, D=8, H=128, E=128, NC=1000, NI=8192
#define NB 16
#define NL 50
#define ND 8
#define NH 128
#define NC 1000
#define NI 8192

// Output flat offsets (return order)
#define OFF_CAT  0
#define OFF_DS   128000
#define OFF_DSC  134400
#define OFF_EMB  1182976
#define OFF_EMBC 1285376
#define OFF_LOSS 2333952

// Workspace layout (floats)
#define WS_SPART 0          // 128*5*128 = 81920  (sum-exp partials per l-chunk)
#define WS_PK    81920      // 800*128   = 102400
#define WS_PKCT  184320     // 128*8192  = 1048576 (transposed [h][i])
#define WS_WP    1232896    // 128*128   = 16384  (W' = Wk @ Wk1)
#define WS_BP    1249280    // 128               (b' = bk @ Wk1)
#define WS_AGG   1249408    // 16*8*128  = 16384
#define WS_PD2   1265792    // 16*8*128  = 16384
// total = 1282176 floats ~= 5.13 MB

// ---------------------------------------------------------------------------
// K0: prep. blocks 0..63: W'[2r..2r+1][:] = Wk[2r..2r+1][:] @ Wk1.
// block 64: b' = bk @ Wk1, and zero the loss accumulator.
__global__ __launch_bounds__(128) void k_prep(
    const float* __restrict__ Wk, const float* __restrict__ bk,
    const float* __restrict__ W1, float* __restrict__ ws_wp,
    float* __restrict__ ws_bp, float* __restrict__ out_loss)
{
    const int t = threadIdx.x;
    const int bxx = blockIdx.x;
    __shared__ float wk_s[256];
    const float* __restrict__ Wk1 = W1 + 128 * 128;
    if (bxx < 64) {
        const int r0 = bxx * 2;
        wk_s[t]       = Wk[r0 * 128 + t];
        wk_s[128 + t] = Wk[(r0 + 1) * 128 + t];
        __syncthreads();
        float a0 = 0.f, a1 = 0.f;
        for (int k = 0; k < 128; k += 4) {
            #pragma unroll
            for (int j = 0; j < 4; ++j) {
                const float w = Wk1[(k + j) * 128 + t];
                a0 = fmaf(wk_s[k + j], w, a0);
                a1 = fmaf(wk_s[128 + k + j], w, a1);
            }
        }
        ws_wp[r0 * 128 + t]       = a0;
        ws_wp[(r0 + 1) * 128 + t] = a1;
    } else {
        wk_s[t] = bk[t];
        __syncthreads();
        float a0 = 0.f;
        for (int k = 0; k < 128; k += 4) {
            #pragma unroll
            for (int j = 0; j < 4; ++j)
                a0 = fmaf(wk_s[k + j], Wk1[(k + j) * 128 + t], a0);
        }
        ws_bp[t] = a0;
        if (t == 0) out_loss[0] = 0.f;
    }
}

// ---------------------------------------------------------------------------
// K1 (one launch, 256 thr): blocks 0..99 session (8 rows: emb out + pk),
// 100..611 candidates (16 rows: emb_cand out + pkcT), 612..1251 dsum partials.
// All roles read only global inputs + K0 outputs -> fully parallel.
__global__ __launch_bounds__(256) void k_main(
    const int* __restrict__ inp, const int* __restrict__ cand,
    const float* __restrict__ emb_table, const float* __restrict__ Wd,
    const float* __restrict__ ws_wp, const float* __restrict__ ws_bp,
    float* __restrict__ out_emb, float* __restrict__ out_embc,
    float* __restrict__ ws_pk, float* __restrict__ ws_pkcT,
    float* __restrict__ ws_spart)
{
    const int bx = blockIdx.x;
    const int t = threadIdx.x;
    const int c = t & 127, g = t >> 7;
    __shared__ __align__(16) float smem[2176];

    if (bx < 100) {
        // ---- session: 8 rows; pk = emb @ W' + b' ----
        const int r0 = bx * 8;
        float* e_s = smem;                       // 1024
        #pragma unroll
        for (int r = 0; r < 4; ++r) {
            const int gr = g * 4 + r;
            const int cat = inp[r0 + gr];
            const float v = emb_table[cat * 128 + c];
            e_s[gr * 128 + c] = v;
            out_emb[(r0 + gr) * 128 + c] = v;
        }
        __syncthreads();
        const float bpv = ws_bp[c];
        float acc[4] = {bpv, bpv, bpv, bpv};
        for (int k = 0; k < 128; k += 4) {
            const float w0 = ws_wp[(k + 0) * 128 + c], w1 = ws_wp[(k + 1) * 128 + c];
            const float w2 = ws_wp[(k + 2) * 128 + c], w3 = ws_wp[(k + 3) * 128 + c];
            #pragma unroll
            for (int r = 0; r < 4; ++r) {
                const float4 e4 = *reinterpret_cast<const float4*>(&e_s[(g * 4 + r) * 128 + k]);
                acc[r] = fmaf(e4.w, w3, fmaf(e4.z, w2, fmaf(e4.y, w1, fmaf(e4.x, w0, acc[r]))));
            }
        }
        #pragma unroll
        for (int r = 0; r < 4; ++r) ws_pk[(r0 + g * 4 + r) * 128 + c] = acc[r];
    } else if (bx < 612) {
        // ---- candidates: 16 rows; pkc = emb_cand @ W' + b', stored [h][i] ----
        const int i0 = (bx - 100) * 16;
        float* e_s = smem;                       // 2048
        #pragma unroll
        for (int r = 0; r < 8; ++r) {
            const int gr = g * 8 + r;
            const int cat = cand[i0 + gr];
            const float v = emb_table[cat * 128 + c];
            e_s[gr * 128 + c] = v;
            out_embc[(i0 + gr) * 128 + c] = v;
        }
        __syncthreads();
        const float bpv = ws_bp[c];
        float acc[8];
        #pragma unroll
        for (int r = 0; r < 8; ++r) acc[r] = bpv;
        for (int k = 0; k < 128; k += 4) {
            const float w0 = ws_wp[(k + 0) * 128 + c], w1 = ws_wp[(k + 1) * 128 + c];
            const float w2 = ws_wp[(k + 2) * 128 + c], w3 = ws_wp[(k + 3) * 128 + c];
            #pragma unroll
            for (int r = 0; r < 8; ++r) {
                const float4 e4 = *reinterpret_cast<const float4*>(&e_s[(g * 8 + r) * 128 + k]);
                acc[r] = fmaf(e4.w, w3, fmaf(e4.z, w2, fmaf(e4.y, w1, fmaf(e4.x, w0, acc[r]))));
            }
        }
        // LDS transpose (stride 132) then 64B-contiguous stores
        __syncthreads();
        float* tb = smem;                        // 16*132 = 2112
        #pragma unroll
        for (int r = 0; r < 8; ++r) tb[(g * 8 + r) * 132 + c] = acc[r];
        __syncthreads();
        #pragma unroll
        for (int p = 0; p < 2; ++p) {
            const int h = p * 64 + (t >> 2);
            const int ib = (t & 3) * 4;
            const float4 v = make_float4(tb[(ib + 0) * 132 + h], tb[(ib + 1) * 132 + h],
                                         tb[(ib + 2) * 132 + h], tb[(ib + 3) * 132 + h]);
            *reinterpret_cast<float4*>(&ws_pkcT[(size_t)h * NI + i0 + ib]) = v;
        }
    } else {
        // ---- dsum partial: Spart[bd][chunk][h] over 10 l's; gathers emb itself ----
        const int idx = bx - 612;
        const int bd = idx / 5, chunk = idx % 5;
        const int b = bd >> 3, d = bd & 7;
        const int half = g;
        float* se = smem;                        // 1280
        float* ss = smem + 1280;                 // 256
        for (int ii = t; ii < 1280; ii += 256) {
            const int row = ii >> 7, col = ii & 127;
            const int cat = inp[b * NL + chunk * 10 + row];
            se[ii] = emb_table[cat * 128 + col];
        }
        __syncthreads();
        const float* __restrict__ wp = Wd + d * 128 + c;
        float acc[5] = {0.f, 0.f, 0.f, 0.f, 0.f};
        const int l0 = half * 5;
        for (int k = 0; k < 128; k += 4) {
            const float w0 = wp[(k + 0) * 1024], w1 = wp[(k + 1) * 1024];
            const float w2 = wp[(k + 2) * 1024], w3 = wp[(k + 3) * 1024];
            #pragma unroll
            for (int li = 0; li < 5; ++li) {
                const float4 e4 = *reinterpret_cast<const float4*>(&se[(l0 + li) * 128 + k]);
                acc[li] = fmaf(e4.w, w3, fmaf(e4.z, w2, fmaf(e4.y, w1, fmaf(e4.x, w0, acc[li]))));
            }
        }
        float s = 0.f;
        #pragma unroll
        for (int li = 0; li < 5; ++li) s += expf(acc[li]);
        ss[half * 128 + c] = s;
        __syncthreads();
        if (half == 0)
            ws_spart[(bd * 5 + chunk) * 128 + c] = ss[c] + ss[128 + c];
    }
}

// ---------------------------------------------------------------------------
// K2: agg = log(sum of partials) ONCE; then pd2 = agg@Wd1+b1 and
// catgy = agg@Wc+bc fused (block per bd = 128 blocks, 256 threads)
__global__ __launch_bounds__(256) void k_agg2(
    const float* __restrict__ ws_spart, const float* __restrict__ W1,
    const float* __restrict__ b1, const float* __restrict__ Wc,
    const float* __restrict__ bc, float* __restrict__ ws_agg,
    float* __restrict__ ws_pd2, float* __restrict__ out_cat)
{
    const int bd = blockIdx.x;
    const int t = threadIdx.x;
    const int c = t & 127, half = t >> 7;
    __shared__ __align__(16) float a_s[128];
    if (half == 0) {
        float s = 0.f;
        #pragma unroll
        for (int ch = 0; ch < 5; ++ch) s += ws_spart[(bd * 5 + ch) * 128 + c];
        const float av = logf(s);
        a_s[c] = av;
        ws_agg[bd * 128 + c] = av;
    }
    __syncthreads();
    if (half == 0) {
        float acc = b1[c];
        for (int k = 0; k < 128; k += 4) {
            acc = fmaf(a_s[k + 0], W1[(k + 0) * 128 + c], acc);
            acc = fmaf(a_s[k + 1], W1[(k + 1) * 128 + c], acc);
            acc = fmaf(a_s[k + 2], W1[(k + 2) * 128 + c], acc);
            acc = fmaf(a_s[k + 3], W1[(k + 3) * 128 + c], acc);
        }
        ws_pd2[bd * 128 + c] = acc;
    }
    float acc4[4];
    int   col4[4];
    #pragma unroll
    for (int j = 0; j < 4; ++j) {
        const int col = t + j * 256;
        col4[j] = (col < NC) ? col : (NC - 1);
        acc4[j] = bc[col4[j]];
    }
    for (int k = 0; k < 128; ++k) {
        const float av = a_s[k];
        const float* wr = Wc + (size_t)k * NC;
        #pragma unroll
        for (int j = 0; j < 4; ++j) acc4[j] = fmaf(av, wr[col4[j]], acc4[j]);
    }
    #pragma unroll
    for (int j = 0; j < 4; ++j) {
        const int col = t + j * 256;
        if (col < NC) out_cat[bd * NC + col] = acc4[j];
    }
}

// ---------------------------------------------------------------------------
// K3: blocks 0..2047 cand_score (2 rows/thread -> 8192 waves = 8/SIMD),
// blocks 2048..2063 per-b loss + demand_score. Small static LDS (~5.8 KB).
__global__ __launch_bounds__(256) void k_tail2(
    const float* __restrict__ ws_agg, const float* __restrict__ ws_pd2,
    const float* __restrict__ ws_pk, const float* __restrict__ ws_pkcT,
    const float* __restrict__ w_score, float* __restrict__ out_ds,
    float* __restrict__ out_dsc, float* __restrict__ out_loss)
{
    const int bx = blockIdx.x;
    const int t = threadIdx.x;
    __shared__ __align__(16) float smem[1440];
    float* pd_s = smem;            // 1024 (cand uses 256)
    float* ws_s = smem + 1024;     // 128
    float* sp   = smem + 1152;     // 256
    float* aux  = smem + 1408;     // normp[16] + wred[4]

    if (bx < 2048) {
        // ---- cand_score: bx = b*128 + rq*32 + ichunk ----
        const int ichunk = bx & 31, rq = (bx >> 5) & 3, b = bx >> 7;
        const int r0 = b * 8 + rq * 2;
        const int i = ichunk * 256 + t;
        pd_s[t] = ws_pd2[r0 * 128 + t];          // 2 rows = 256 floats
        if (t < 128) ws_s[t] = w_score[t];
        __syncthreads();
        float a0 = 0.f, a1 = 0.f;
        for (int h = 0; h < 128; h += 4) {
            const float pv0 = ws_pkcT[(size_t)(h + 0) * NI + i];
            const float pv1 = ws_pkcT[(size_t)(h + 1) * NI + i];
            const float pv2 = ws_pkcT[(size_t)(h + 2) * NI + i];
            const float pv3 = ws_pkcT[(size_t)(h + 3) * NI + i];
            const float4 w4 = *reinterpret_cast<const float4*>(&ws_s[h]);
            const float4 p0 = *reinterpret_cast<const float4*>(&pd_s[h]);
            const float4 p1 = *reinterpret_cast<const float4*>(&pd_s[128 + h]);
            a0 = fmaf(fmaxf(p0.x + pv0, 0.f), w4.x, a0);
            a0 = fmaf(fmaxf(p0.y + pv1, 0.f), w4.y, a0);
            a0 = fmaf(fmaxf(p0.z + pv2, 0.f), w4.z, a0);
            a0 = fmaf(fmaxf(p0.w + pv3, 0.f), w4.w, a0);
            a1 = fmaf(fmaxf(p1.x + pv0, 0.f), w4.x, a1);
            a1 = fmaf(fmaxf(p1.y + pv1, 0.f), w4.y, a1);
            a1 = fmaf(fmaxf(p1.z + pv2, 0.f), w4.z, a1);
            a1 = fmaf(fmaxf(p1.w + pv3, 0.f), w4.w, a1);
        }
        out_dsc[(size_t)(r0 + 0) * NI + i] = a0;
        out_dsc[(size_t)(r0 + 1) * NI + i] = a1;
    } else {
        // ---- per-b loss + demand_score (reads precomputed agg/pd2) ----
        const int b = bx - 2048;
        const int c = t & 127, g = t >> 7;
        const int w = t >> 6, lane = t & 63;
        float* normp = aux;            // [4][4]
        float* wred  = aux + 16;       // [4]
        for (int j = t; j < 1024; j += 256) pd_s[j] = ws_pd2[(b * 8) * 128 + j];
        if (t < 128) ws_s[t] = w_score[t];
        // ---- loss ----
        float a[4];
        #pragma unroll
        for (int r = 0; r < 4; ++r) a[r] = ws_agg[(b * 8 + g * 4 + r) * 128 + c];
        #pragma unroll
        for (int r = 0; r < 4; ++r) {
            float s = a[r] * a[r];
            s += __shfl_down(s, 32); s += __shfl_down(s, 16); s += __shfl_down(s, 8);
            s += __shfl_down(s, 4);  s += __shfl_down(s, 2);  s += __shfl_down(s, 1);
            if (lane == 0) normp[w * 4 + r] = s;
        }
        __syncthreads();
        float Sp = 0.f;
        #pragma unroll
        for (int r = 0; r < 4; ++r) {
            const float nsq = normp[(2 * g) * 4 + r] + normp[(2 * g + 1) * 4 + r];
            const float iv = 1.f / (sqrtf(nsq) + 1e-12f);
            Sp = fmaf(a[r], iv, Sp);
        }
        sp[g * 128 + c] = Sp;
        __syncthreads();
        float p = 0.f;
        if (t < 128) {
            const float S = sp[c] + sp[128 + c];
            p = S * S;
        }
        p += __shfl_down(p, 32); p += __shfl_down(p, 16); p += __shfl_down(p, 8);
        p += __shfl_down(p, 4);  p += __shfl_down(p, 2);  p += __shfl_down(p, 1);
        if (lane == 0) wred[w] = p;
        __syncthreads();
        if (t == 0) {
            float corr = 0.f;
            #pragma unroll
            for (int d = 0; d < 8; ++d) {
                const float nsq = normp[(2 * (d >> 2)) * 4 + (d & 3)] +
                                  normp[(2 * (d >> 2) + 1) * 4 + (d & 3)];
                const float iv = 1.f / (sqrtf(nsq) + 1e-12f);
                corr = fmaf(nsq, iv * iv, corr);
            }
            atomicAdd(out_loss,
                      (wred[0] + wred[1] + wred[2] + wred[3] - corr) * (1.0f / 896.0f));
        }
        // ---- demand_score: all 400 (l,d) pairs; pk coalesced from L2 ----
        const float* __restrict__ pk_g = ws_pk + (size_t)b * NL * 128;
        for (int pp = w; pp < 400; pp += 4) {
            const int l = pp >> 3, d = pp & 7;
            float v = fmaxf(pd_s[d * 128 + lane] + pk_g[l * 128 + lane], 0.f) * ws_s[lane]
                    + fmaxf(pd_s[d * 128 + 64 + lane] + pk_g[l * 128 + 64 + lane], 0.f) * ws_s[64 + lane];
            v += __shfl_down(v, 32); v += __shfl_down(v, 16); v += __shfl_down(v, 8);
            v += __shfl_down(v, 4);  v += __shfl_down(v, 2);  v += __shfl_down(v, 1);
            if (lane == 0) out_ds[b * 400 + l * 8 + d] = v;
        }
    }
}

// ---------------------------------------------------------------------------
extern "C" void kernel_launch(void* const* d_in, const int* in_sizes, int n_in,
                              void* d_out, int out_size, void* d_ws, size_t ws_size,
                              hipStream_t stream)
{
    const int*   input     = (const int*)d_in[0];
    const int*   cand      = (const int*)d_in[1];
    const float* emb_table = (const float*)d_in[4];
    const float* Wd        = (const float*)d_in[5];
    const float* Wk        = (const float*)d_in[6];
    const float* bk        = (const float*)d_in[7];
    const float* W1        = (const float*)d_in[8];
    const float* b1        = (const float*)d_in[9];
    const float* w_score   = (const float*)d_in[10];
    const float* Wc        = (const float*)d_in[11];
    const float* bc        = (const float*)d_in[12];

    float* out = (float*)d_out;
    float* out_cat  = out + OFF_CAT;
    float* out_ds   = out + OFF_DS;
    float* out_dsc  = out + OFF_DSC;
    float* out_emb  = out + OFF_EMB;
    float* out_embc = out + OFF_EMBC;
    float* out_loss = out + OFF_LOSS;

    float* ws       = (float*)d_ws;
    float* ws_spart = ws + WS_SPART;
    float* ws_pk    = ws + WS_PK;
    float* ws_pkcT  = ws + WS_PKCT;
    float* ws_wp    = ws + WS_WP;
    float* ws_bp    = ws + WS_BP;
    float* ws_agg   = ws + WS_AGG;
    float* ws_pd2   = ws + WS_PD2;

    k_prep<<<65, 128, 0, stream>>>(Wk, bk, W1, ws_wp, ws_bp, out_loss);
    k_main<<<1252, 256, 0, stream>>>(input, cand, emb_table, Wd, ws_wp, ws_bp,
                                     out_emb, out_embc, ws_pk, ws_pkcT, ws_spart);
    k_agg2<<<128, 256, 0, stream>>>(ws_spart, W1, b1, Wc, bc, ws_agg, ws_pd2, out_cat);
    k_tail2<<<2064, 256, 0, stream>>>(ws_agg, ws_pd2, ws_pk, ws_pkcT, w_score,
                                      out_ds, out_dsc, out_loss);
}

// Round 8
// 128.041 us; speedup vs baseline: 1.3151x; 1.3151x over previous
//
#include <hip/hip_runtime.h>
#include <hip/hip_bf16.h>

// Problem constants: B=16, L=50, D=8, H=128, E=128, NC=1000, NI=8192
#define NB 16
#define NL 50
#define ND 8
#define NH 128
#define NC 1000
#define NI 8192

// Output flat offsets (return order)
#define OFF_CAT  0
#define OFF_DS   128000
#define OFF_DSC  134400
#define OFF_EMB  1182976
#define OFF_EMBC 1285376
#define OFF_LOSS 2333952

// Workspace layout (floats)
#define WS_SPART 0          // 128*5*128 = 81920  (sum-exp partials per l-chunk)
#define WS_PK    81920      // 800*128   = 102400
#define WS_PKCT  184320     // 128*8192  = 1048576 (transposed [h][i])
#define WS_WP    1232896    // 128*128   = 16384  (W' = Wk @ Wk1)
#define WS_BP    1249280    // 128               (b' = bk @ Wk1)
#define WS_AGG   1249408    // 16*8*128  = 16384
#define WS_PD2   1265792    // 16*8*128  = 16384
// total = 1282176 floats ~= 5.13 MB

// ---------------------------------------------------------------------------
// K0: prep. blocks 0..63: W'[2r..2r+1][:] = Wk[2r..2r+1][:] @ Wk1.
// block 64: b' = bk @ Wk1, and zero the loss accumulator.
__global__ __launch_bounds__(128) void k_prep(
    const float* __restrict__ Wk, const float* __restrict__ bk,
    const float* __restrict__ W1, float* __restrict__ ws_wp,
    float* __restrict__ ws_bp, float* __restrict__ out_loss)
{
    const int t = threadIdx.x;
    const int bxx = blockIdx.x;
    __shared__ float wk_s[256];
    const float* __restrict__ Wk1 = W1 + 128 * 128;
    if (bxx < 64) {
        const int r0 = bxx * 2;
        wk_s[t]       = Wk[r0 * 128 + t];
        wk_s[128 + t] = Wk[(r0 + 1) * 128 + t];
        __syncthreads();
        float a0 = 0.f, a1 = 0.f;
        for (int k = 0; k < 128; k += 4) {
            #pragma unroll
            for (int j = 0; j < 4; ++j) {
                const float w = Wk1[(k + j) * 128 + t];
                a0 = fmaf(wk_s[k + j], w, a0);
                a1 = fmaf(wk_s[128 + k + j], w, a1);
            }
        }
        ws_wp[r0 * 128 + t]       = a0;
        ws_wp[(r0 + 1) * 128 + t] = a1;
    } else {
        wk_s[t] = bk[t];
        __syncthreads();
        float a0 = 0.f;
        for (int k = 0; k < 128; k += 4) {
            #pragma unroll
            for (int j = 0; j < 4; ++j)
                a0 = fmaf(wk_s[k + j], Wk1[(k + j) * 128 + t], a0);
        }
        ws_bp[t] = a0;
        if (t == 0) out_loss[0] = 0.f;
    }
}

// ---------------------------------------------------------------------------
// K1 (one launch, 256 thr): blocks 0..99 session (8 rows: emb out + pk),
// 100..611 candidates (16 rows: emb_cand out + pkcT), 612..1251 dsum partials.
// All roles read only global inputs + K0 outputs -> fully parallel.
__global__ __launch_bounds__(256) void k_main(
    const int* __restrict__ inp, const int* __restrict__ cand,
    const float* __restrict__ emb_table, const float* __restrict__ Wd,
    const float* __restrict__ ws_wp, const float* __restrict__ ws_bp,
    float* __restrict__ out_emb, float* __restrict__ out_embc,
    float* __restrict__ ws_pk, float* __restrict__ ws_pkcT,
    float* __restrict__ ws_spart)
{
    const int bx = blockIdx.x;
    const int t = threadIdx.x;
    const int c = t & 127, g = t >> 7;
    __shared__ __align__(16) float smem[2176];

    if (bx < 100) {
        // ---- session: 8 rows; pk = emb @ W' + b' ----
        const int r0 = bx * 8;
        float* e_s = smem;                       // 1024
        #pragma unroll
        for (int r = 0; r < 4; ++r) {
            const int gr = g * 4 + r;
            const int cat = inp[r0 + gr];
            const float v = emb_table[cat * 128 + c];
            e_s[gr * 128 + c] = v;
            out_emb[(r0 + gr) * 128 + c] = v;
        }
        __syncthreads();
        const float bpv = ws_bp[c];
        float acc[4] = {bpv, bpv, bpv, bpv};
        for (int k = 0; k < 128; k += 4) {
            const float w0 = ws_wp[(k + 0) * 128 + c], w1 = ws_wp[(k + 1) * 128 + c];
            const float w2 = ws_wp[(k + 2) * 128 + c], w3 = ws_wp[(k + 3) * 128 + c];
            #pragma unroll
            for (int r = 0; r < 4; ++r) {
                const float4 e4 = *reinterpret_cast<const float4*>(&e_s[(g * 4 + r) * 128 + k]);
                acc[r] = fmaf(e4.w, w3, fmaf(e4.z, w2, fmaf(e4.y, w1, fmaf(e4.x, w0, acc[r]))));
            }
        }
        #pragma unroll
        for (int r = 0; r < 4; ++r) ws_pk[(r0 + g * 4 + r) * 128 + c] = acc[r];
    } else if (bx < 612) {
        // ---- candidates: 16 rows; pkc = emb_cand @ W' + b', stored [h][i] ----
        const int i0 = (bx - 100) * 16;
        float* e_s = smem;                       // 2048
        #pragma unroll
        for (int r = 0; r < 8; ++r) {
            const int gr = g * 8 + r;
            const int cat = cand[i0 + gr];
            const float v = emb_table[cat * 128 + c];
            e_s[gr * 128 + c] = v;
            out_embc[(i0 + gr) * 128 + c] = v;
        }
        __syncthreads();
        const float bpv = ws_bp[c];
        float acc[8];
        #pragma unroll
        for (int r = 0; r < 8; ++r) acc[r] = bpv;
        for (int k = 0; k < 128; k += 4) {
            const float w0 = ws_wp[(k + 0) * 128 + c], w1 = ws_wp[(k + 1) * 128 + c];
            const float w2 = ws_wp[(k + 2) * 128 + c], w3 = ws_wp[(k + 3) * 128 + c];
            #pragma unroll
            for (int r = 0; r < 8; ++r) {
                const float4 e4 = *reinterpret_cast<const float4*>(&e_s[(g * 8 + r) * 128 + k]);
                acc[r] = fmaf(e4.w, w3, fmaf(e4.z, w2, fmaf(e4.y, w1, fmaf(e4.x, w0, acc[r]))));
            }
        }
        // LDS transpose (stride 132) then 64B-contiguous stores
        __syncthreads();
        float* tb = smem;                        // 16*132 = 2112
        #pragma unroll
        for (int r = 0; r < 8; ++r) tb[(g * 8 + r) * 132 + c] = acc[r];
        __syncthreads();
        #pragma unroll
        for (int p = 0; p < 2; ++p) {
            const int h = p * 64 + (t >> 2);
            const int ib = (t & 3) * 4;
            const float4 v = make_float4(tb[(ib + 0) * 132 + h], tb[(ib + 1) * 132 + h],
                                         tb[(ib + 2) * 132 + h], tb[(ib + 3) * 132 + h]);
            *reinterpret_cast<float4*>(&ws_pkcT[(size_t)h * NI + i0 + ib]) = v;
        }
    } else {
        // ---- dsum partial: Spart[bd][chunk][h] over 10 l's; gathers emb itself ----
        const int idx = bx - 612;
        const int bd = idx / 5, chunk = idx % 5;
        const int b = bd >> 3, d = bd & 7;
        const int half = g;
        float* se = smem;                        // 1280
        float* ss = smem + 1280;                 // 256
        for (int ii = t; ii < 1280; ii += 256) {
            const int row = ii >> 7, col = ii & 127;
            const int cat = inp[b * NL + chunk * 10 + row];
            se[ii] = emb_table[cat * 128 + col];
        }
        __syncthreads();
        const float* __restrict__ wp = Wd + d * 128 + c;
        float acc[5] = {0.f, 0.f, 0.f, 0.f, 0.f};
        const int l0 = half * 5;
        for (int k = 0; k < 128; k += 4) {
            const float w0 = wp[(k + 0) * 1024], w1 = wp[(k + 1) * 1024];
            const float w2 = wp[(k + 2) * 1024], w3 = wp[(k + 3) * 1024];
            #pragma unroll
            for (int li = 0; li < 5; ++li) {
                const float4 e4 = *reinterpret_cast<const float4*>(&se[(l0 + li) * 128 + k]);
                acc[li] = fmaf(e4.w, w3, fmaf(e4.z, w2, fmaf(e4.y, w1, fmaf(e4.x, w0, acc[li]))));
            }
        }
        float s = 0.f;
        #pragma unroll
        for (int li = 0; li < 5; ++li) s += expf(acc[li]);
        ss[half * 128 + c] = s;
        __syncthreads();
        if (half == 0)
            ws_spart[(bd * 5 + chunk) * 128 + c] = ss[c] + ss[128 + c];
    }
}

// ---------------------------------------------------------------------------
// K2: agg = log(sum of partials) ONCE; then pd2 = agg@Wd1+b1 and
// catgy = agg@Wc+bc fused (block per bd = 128 blocks, 256 threads)
__global__ __launch_bounds__(256) void k_agg2(
    const float* __restrict__ ws_spart, const float* __restrict__ W1,
    const float* __restrict__ b1, const float* __restrict__ Wc,
    const float* __restrict__ bc, float* __restrict__ ws_agg,
    float* __restrict__ ws_pd2, float* __restrict__ out_cat)
{
    const int bd = blockIdx.x;
    const int t = threadIdx.x;
    const int c = t & 127, half = t >> 7;
    __shared__ __align__(16) float a_s[128];
    if (half == 0) {
        float s = 0.f;
        #pragma unroll
        for (int ch = 0; ch < 5; ++ch) s += ws_spart[(bd * 5 + ch) * 128 + c];
        const float av = logf(s);
        a_s[c] = av;
        ws_agg[bd * 128 + c] = av;
    }
    __syncthreads();
    if (half == 0) {
        float acc = b1[c];
        for (int k = 0; k < 128; k += 4) {
            acc = fmaf(a_s[k + 0], W1[(k + 0) * 128 + c], acc);
            acc = fmaf(a_s[k + 1], W1[(k + 1) * 128 + c], acc);
            acc = fmaf(a_s[k + 2], W1[(k + 2) * 128 + c], acc);
            acc = fmaf(a_s[k + 3], W1[(k + 3) * 128 + c], acc);
        }
        ws_pd2[bd * 128 + c] = acc;
    }
    float acc4[4];
    int   col4[4];
    #pragma unroll
    for (int j = 0; j < 4; ++j) {
        const int col = t + j * 256;
        col4[j] = (col < NC) ? col : (NC - 1);
        acc4[j] = bc[col4[j]];
    }
    for (int k = 0; k < 128; ++k) {
        const float av = a_s[k];
        const float* wr = Wc + (size_t)k * NC;
        #pragma unroll
        for (int j = 0; j < 4; ++j) acc4[j] = fmaf(av, wr[col4[j]], acc4[j]);
    }
    #pragma unroll
    for (int j = 0; j < 4; ++j) {
        const int col = t + j * 256;
        if (col < NC) out_cat[bd * NC + col] = acc4[j];
    }
}

// ---------------------------------------------------------------------------
// K3: blocks 0..1023 cand_score (4 rows/thread, prefetched pkcT stream),
// blocks 1024..1823 demand_score (one (b,l) each — parallel, no stragglers),
// blocks 1824..1839 per-b loss.
__global__ __launch_bounds__(256) void k_tail3(
    const float* __restrict__ ws_agg, const float* __restrict__ ws_pd2,
    const float* __restrict__ ws_pk, const float* __restrict__ ws_pkcT,
    const float* __restrict__ w_score, float* __restrict__ out_ds,
    float* __restrict__ out_dsc, float* __restrict__ out_loss)
{
    const int bx = blockIdx.x;
    const int t = threadIdx.x;
    __shared__ __align__(16) float smem[928];
    float* pd_s = smem;            // 512 (cand rows)
    float* ws_s = smem + 512;      // 128
    float* sp   = smem + 640;      // 256 (loss)
    float* aux  = smem + 896;      // normp[16] + wred[4] + red[16]

    if (bx < 1024) {
        // ---- cand_score: bx = b*64 + rh*32 + ichunk; 4 rows/thread ----
        const int ichunk = bx & 31, rh = (bx >> 5) & 1, b = bx >> 6;
        const int r0 = b * 8 + rh * 4;
        const int i = ichunk * 256 + t;
        for (int j = t; j < 512; j += 256) pd_s[j] = ws_pd2[r0 * 128 + j];
        if (t < 128) ws_s[t] = w_score[t];
        __syncthreads();
        float a0 = 0.f, a1 = 0.f, a2 = 0.f, a3 = 0.f;
        const float* __restrict__ pc0 = ws_pkcT + i;
        float4 pv = make_float4(pc0[0], pc0[NI], pc0[2 * NI], pc0[3 * NI]);
        for (int h = 0; h < 128; h += 4) {
            const float4 cur = pv;
            if (h + 4 < 128) {
                const float* __restrict__ pn = ws_pkcT + (size_t)(h + 4) * NI + i;
                pv = make_float4(pn[0], pn[NI], pn[2 * NI], pn[3 * NI]);
            }
            const float4 w4 = *reinterpret_cast<const float4*>(&ws_s[h]);
            const float4 p0 = *reinterpret_cast<const float4*>(&pd_s[h]);
            const float4 p1 = *reinterpret_cast<const float4*>(&pd_s[128 + h]);
            const float4 p2 = *reinterpret_cast<const float4*>(&pd_s[256 + h]);
            const float4 p3 = *reinterpret_cast<const float4*>(&pd_s[384 + h]);
            a0 = fmaf(fmaxf(p0.x + cur.x, 0.f), w4.x, a0);
            a0 = fmaf(fmaxf(p0.y + cur.y, 0.f), w4.y, a0);
            a0 = fmaf(fmaxf(p0.z + cur.z, 0.f), w4.z, a0);
            a0 = fmaf(fmaxf(p0.w + cur.w, 0.f), w4.w, a0);
            a1 = fmaf(fmaxf(p1.x + cur.x, 0.f), w4.x, a1);
            a1 = fmaf(fmaxf(p1.y + cur.y, 0.f), w4.y, a1);
            a1 = fmaf(fmaxf(p1.z + cur.z, 0.f), w4.z, a1);
            a1 = fmaf(fmaxf(p1.w + cur.w, 0.f), w4.w, a1);
            a2 = fmaf(fmaxf(p2.x + cur.x, 0.f), w4.x, a2);
            a2 = fmaf(fmaxf(p2.y + cur.y, 0.f), w4.y, a2);
            a2 = fmaf(fmaxf(p2.z + cur.z, 0.f), w4.z, a2);
            a2 = fmaf(fmaxf(p2.w + cur.w, 0.f), w4.w, a2);
            a3 = fmaf(fmaxf(p3.x + cur.x, 0.f), w4.x, a3);
            a3 = fmaf(fmaxf(p3.y + cur.y, 0.f), w4.y, a3);
            a3 = fmaf(fmaxf(p3.z + cur.z, 0.f), w4.z, a3);
            a3 = fmaf(fmaxf(p3.w + cur.w, 0.f), w4.w, a3);
        }
        out_dsc[(size_t)(r0 + 0) * NI + i] = a0;
        out_dsc[(size_t)(r0 + 1) * NI + i] = a1;
        out_dsc[(size_t)(r0 + 2) * NI + i] = a2;
        out_dsc[(size_t)(r0 + 3) * NI + i] = a3;
    } else if (bx < 1824) {
        // ---- demand_score: one (b,l) per block; group g covers d=g*4..g*4+3 ----
        const int bl = bx - 1024;
        const int b = bl / 50, l = bl % 50;
        const int c = t & 127, g = t >> 7;
        const int w = t >> 6, lane = t & 63;
        float* red = aux;                      // [4][4]
        const float pkv = ws_pk[(size_t)bl * 128 + c];
        const float wv = w_score[c];
        #pragma unroll
        for (int r = 0; r < 4; ++r) {
            const int d = g * 4 + r;
            float v = fmaxf(ws_pd2[(b * 8 + d) * 128 + c] + pkv, 0.f) * wv;
            v += __shfl_down(v, 32); v += __shfl_down(v, 16); v += __shfl_down(v, 8);
            v += __shfl_down(v, 4);  v += __shfl_down(v, 2);  v += __shfl_down(v, 1);
            if (lane == 0) red[w * 4 + r] = v;
        }
        __syncthreads();
        if (t < 8) {
            const int gg = t >> 2, rr = t & 3;
            out_ds[b * 400 + l * 8 + t] = red[(2 * gg) * 4 + rr] + red[(2 * gg + 1) * 4 + rr];
        }
    } else {
        // ---- loss: block per b; loss_b = sum_h S_h^2 - sum_d nsq_d*iv_d^2 ----
        const int b = bx - 1824;
        const int c = t & 127, g = t >> 7;
        const int w = t >> 6, lane = t & 63;
        float* normp = aux;            // [4][4]
        float* wred  = aux + 16;       // [4]
        float a[4];
        #pragma unroll
        for (int r = 0; r < 4; ++r) a[r] = ws_agg[(b * 8 + g * 4 + r) * 128 + c];
        #pragma unroll
        for (int r = 0; r < 4; ++r) {
            float s = a[r] * a[r];
            s += __shfl_down(s, 32); s += __shfl_down(s, 16); s += __shfl_down(s, 8);
            s += __shfl_down(s, 4);  s += __shfl_down(s, 2);  s += __shfl_down(s, 1);
            if (lane == 0) normp[w * 4 + r] = s;
        }
        __syncthreads();
        float Sp = 0.f;
        #pragma unroll
        for (int r = 0; r < 4; ++r) {
            const float nsq = normp[(2 * g) * 4 + r] + normp[(2 * g + 1) * 4 + r];
            const float iv = 1.f / (sqrtf(nsq) + 1e-12f);
            Sp = fmaf(a[r], iv, Sp);
        }
        sp[g * 128 + c] = Sp;
        __syncthreads();
        float p = 0.f;
        if (t < 128) {
            const float S = sp[c] + sp[128 + c];
            p = S * S;
        }
        p += __shfl_down(p, 32); p += __shfl_down(p, 16); p += __shfl_down(p, 8);
        p += __shfl_down(p, 4);  p += __shfl_down(p, 2);  p += __shfl_down(p, 1);
        if (lane == 0) wred[w] = p;
        __syncthreads();
        if (t == 0) {
            float corr = 0.f;
            #pragma unroll
            for (int d = 0; d < 8; ++d) {
                const float nsq = normp[(2 * (d >> 2)) * 4 + (d & 3)] +
                                  normp[(2 * (d >> 2) + 1) * 4 + (d & 3)];
                const float iv = 1.f / (sqrtf(nsq) + 1e-12f);
                corr = fmaf(nsq, iv * iv, corr);
            }
            atomicAdd(out_loss,
                      (wred[0] + wred[1] + wred[2] + wred[3] - corr) * (1.0f / 896.0f));
        }
    }
}

// ---------------------------------------------------------------------------
extern "C" void kernel_launch(void* const* d_in, const int* in_sizes, int n_in,
                              void* d_out, int out_size, void* d_ws, size_t ws_size,
                              hipStream_t stream)
{
    const int*   input     = (const int*)d_in[0];
    const int*   cand      = (const int*)d_in[1];
    const float* emb_table = (const float*)d_in[4];
    const float* Wd        = (const float*)d_in[5];
    const float* Wk        = (const float*)d_in[6];
    const float* bk        = (const float*)d_in[7];
    const float* W1        = (const float*)d_in[8];
    const float* b1        = (const float*)d_in[9];
    const float* w_score   = (const float*)d_in[10];
    const float* Wc        = (const float*)d_in[11];
    const float* bc        = (const float*)d_in[12];

    float* out = (float*)d_out;
    float* out_cat  = out + OFF_CAT;
    float* out_ds   = out + OFF_DS;
    float* out_dsc  = out + OFF_DSC;
    float* out_emb  = out + OFF_EMB;
    float* out_embc = out + OFF_EMBC;
    float* out_loss = out + OFF_LOSS;

    float* ws       = (float*)d_ws;
    float* ws_spart = ws + WS_SPART;
    float* ws_pk    = ws + WS_PK;
    float* ws_pkcT  = ws + WS_PKCT;
    float* ws_wp    = ws + WS_WP;
    float* ws_bp    = ws + WS_BP;
    float* ws_agg   = ws + WS_AGG;
    float* ws_pd2   = ws + WS_PD2;

    k_prep<<<65, 128, 0, stream>>>(Wk, bk, W1, ws_wp, ws_bp, out_loss);
    k_main<<<1252, 256, 0, stream>>>(input, cand, emb_table, Wd, ws_wp, ws_bp,
                                     out_emb, out_embc, ws_pk, ws_pkcT, ws_spart);
    k_agg2<<<128, 256, 0, stream>>>(ws_spart, W1, b1, Wc, bc, ws_agg, ws_pd2, out_cat);
    k_tail3<<<1840, 256, 0, stream>>>(ws_agg, ws_pd2, ws_pk, ws_pkcT, w_score,
                                      out_ds, out_dsc, out_loss);
}

// Round 10
// 119.296 us; speedup vs baseline: 1.4116x; 1.0733x over previous
//
#include <hip/hip_runtime.h>
#include <hip/hip_bf16.h>

// Problem constants: B=16, L=50, D=8, H=128, E=128, NC=1000, NI=8192
#define NB 16
#define NL 50
#define ND 8
#define NH 128
#define NC 1000
#define NI 8192

// Output flat offsets (return order)
#define OFF_CAT  0
#define OFF_DS   128000
#define OFF_DSC  134400
#define OFF_EMB  1182976
#define OFF_EMBC 1285376
#define OFF_LOSS 2333952

// Workspace layout (floats)
#define WS_SPART 0          // 128*5*128 = 81920
#define WS_PK    81920      // 800*128   = 102400
#define WS_PKCT  184320     // 128*8192  = 1048576 (transposed [h][i])
#define WS_WP    1232896    // 128*128   = 16384  (W' = Wk @ Wk1)
#define WS_BP    1249280    // 128               (b' = bk @ Wk1)
#define WS_AGG   1249408    // 16*8*128  = 16384
#define WS_PD2   1265792    // 16*8*128  = 16384

// ---------------------------------------------------------------------------
// K1 (705 blocks): bx 0..63 W' rows (2/block), bx 64 b' + loss zero,
// bx 65..704 dsum partials. All roles read only raw inputs.
__global__ __launch_bounds__(256) void k_stage0(
    const int* __restrict__ inp, const float* __restrict__ emb_table,
    const float* __restrict__ Wd, const float* __restrict__ Wk,
    const float* __restrict__ bk, const float* __restrict__ W1,
    float* __restrict__ ws_wp, float* __restrict__ ws_bp,
    float* __restrict__ ws_spart, float* __restrict__ out_loss)
{
    const int bx = blockIdx.x;
    const int t = threadIdx.x;
    const int c = t & 127, g = t >> 7;
    __shared__ __align__(16) float smem[1536];

    if (bx < 64) {
        // ---- W'[r0+g][:] = Wk[r0+g][:] @ Wk1 (256 thr: 2 rows at once) ----
        float* wk_s = smem;                        // 256
        const float* __restrict__ Wk1 = W1 + 128 * 128;
        const int r0 = bx * 2;
        wk_s[t] = Wk[(r0 + g) * 128 + c];
        __syncthreads();
        float a = 0.f;
        for (int k = 0; k < 128; k += 4) {
            #pragma unroll
            for (int j = 0; j < 4; ++j)
                a = fmaf(wk_s[g * 128 + k + j], Wk1[(k + j) * 128 + c], a);
        }
        ws_wp[(r0 + g) * 128 + c] = a;
    } else if (bx == 64) {
        float* wk_s = smem;
        const float* __restrict__ Wk1 = W1 + 128 * 128;
        if (t < 128) wk_s[t] = bk[t];
        __syncthreads();
        if (t < 128) {
            float a = 0.f;
            for (int k = 0; k < 128; k += 4) {
                #pragma unroll
                for (int j = 0; j < 4; ++j)
                    a = fmaf(wk_s[k + j], Wk1[(k + j) * 128 + t], a);
            }
            ws_bp[t] = a;
        }
        if (t == 0) out_loss[0] = 0.f;
    } else {
        // ---- dsum partial: Spart[bd][chunk][h] over 10 l's ----
        const int idx = bx - 65;
        const int bd = idx / 5, chunk = idx % 5;
        const int b = bd >> 3, d = bd & 7;
        float* se = smem;                          // 1280
        float* ss = smem + 1280;                   // 256
        for (int ii = t; ii < 1280; ii += 256) {
            const int row = ii >> 7, col = ii & 127;
            const int cat = inp[b * NL + chunk * 10 + row];
            se[ii] = emb_table[cat * 128 + col];
        }
        __syncthreads();
        const float* __restrict__ wp = Wd + d * 128 + c;
        float acc[5] = {0.f, 0.f, 0.f, 0.f, 0.f};
        const int l0 = g * 5;
        for (int k = 0; k < 128; k += 4) {
            const float w0 = wp[(k + 0) * 1024], w1 = wp[(k + 1) * 1024];
            const float w2 = wp[(k + 2) * 1024], w3 = wp[(k + 3) * 1024];
            #pragma unroll
            for (int li = 0; li < 5; ++li) {
                const float4 e4 = *reinterpret_cast<const float4*>(&se[(l0 + li) * 128 + k]);
                acc[li] = fmaf(e4.w, w3, fmaf(e4.z, w2, fmaf(e4.y, w1, fmaf(e4.x, w0, acc[li]))));
            }
        }
        float s = 0.f;
        #pragma unroll
        for (int li = 0; li < 5; ++li) s += expf(acc[li]);
        ss[g * 128 + c] = s;
        __syncthreads();
        if (g == 0)
            ws_spart[(bd * 5 + chunk) * 128 + c] = ss[c] + ss[128 + c];
    }
}

// ---------------------------------------------------------------------------
// K2 (740 blocks): bx 0..99 session pk, 100..611 cand pkcT,
// 612..739 agg = log(sum spart) + pd2 + catgy. Depends only on K1 outputs.
__global__ __launch_bounds__(256) void k_stage1(
    const int* __restrict__ inp, const int* __restrict__ cand,
    const float* __restrict__ emb_table, const float* __restrict__ W1,
    const float* __restrict__ b1, const float* __restrict__ Wc,
    const float* __restrict__ bc, const float* __restrict__ ws_wp,
    const float* __restrict__ ws_bp, const float* __restrict__ ws_spart,
    float* __restrict__ out_emb, float* __restrict__ out_embc,
    float* __restrict__ out_cat, float* __restrict__ ws_pk,
    float* __restrict__ ws_pkcT, float* __restrict__ ws_agg,
    float* __restrict__ ws_pd2)
{
    const int bx = blockIdx.x;
    const int t = threadIdx.x;
    const int c = t & 127, g = t >> 7;
    __shared__ __align__(16) float smem[2176];

    if (bx < 100) {
        // ---- session: 8 rows; pk = emb @ W' + b' ----
        const int r0 = bx * 8;
        float* e_s = smem;                         // 1024
        #pragma unroll
        for (int r = 0; r < 4; ++r) {
            const int gr = g * 4 + r;
            const int cat = inp[r0 + gr];
            const float v = emb_table[cat * 128 + c];
            e_s[gr * 128 + c] = v;
            out_emb[(r0 + gr) * 128 + c] = v;
        }
        __syncthreads();
        const float bpv = ws_bp[c];
        float acc[4] = {bpv, bpv, bpv, bpv};
        for (int k = 0; k < 128; k += 4) {
            const float w0 = ws_wp[(k + 0) * 128 + c], w1 = ws_wp[(k + 1) * 128 + c];
            const float w2 = ws_wp[(k + 2) * 128 + c], w3 = ws_wp[(k + 3) * 128 + c];
            #pragma unroll
            for (int r = 0; r < 4; ++r) {
                const float4 e4 = *reinterpret_cast<const float4*>(&e_s[(g * 4 + r) * 128 + k]);
                acc[r] = fmaf(e4.w, w3, fmaf(e4.z, w2, fmaf(e4.y, w1, fmaf(e4.x, w0, acc[r]))));
            }
        }
        #pragma unroll
        for (int r = 0; r < 4; ++r) ws_pk[(r0 + g * 4 + r) * 128 + c] = acc[r];
    } else if (bx < 612) {
        // ---- candidates: 16 rows; pkc = emb_cand @ W' + b', stored [h][i] ----
        const int i0 = (bx - 100) * 16;
        float* e_s = smem;                         // 2048
        #pragma unroll
        for (int r = 0; r < 8; ++r) {
            const int gr = g * 8 + r;
            const int cat = cand[i0 + gr];
            const float v = emb_table[cat * 128 + c];
            e_s[gr * 128 + c] = v;
            out_embc[(i0 + gr) * 128 + c] = v;
        }
        __syncthreads();
        const float bpv = ws_bp[c];
        float acc[8];
        #pragma unroll
        for (int r = 0; r < 8; ++r) acc[r] = bpv;
        for (int k = 0; k < 128; k += 4) {
            const float w0 = ws_wp[(k + 0) * 128 + c], w1 = ws_wp[(k + 1) * 128 + c];
            const float w2 = ws_wp[(k + 2) * 128 + c], w3 = ws_wp[(k + 3) * 128 + c];
            #pragma unroll
            for (int r = 0; r < 8; ++r) {
                const float4 e4 = *reinterpret_cast<const float4*>(&e_s[(g * 8 + r) * 128 + k]);
                acc[r] = fmaf(e4.w, w3, fmaf(e4.z, w2, fmaf(e4.y, w1, fmaf(e4.x, w0, acc[r]))));
            }
        }
        // LDS transpose (stride 132) then 64B-contiguous stores
        __syncthreads();
        float* tb = smem;                          // 16*132 = 2112
        #pragma unroll
        for (int r = 0; r < 8; ++r) tb[(g * 8 + r) * 132 + c] = acc[r];
        __syncthreads();
        #pragma unroll
        for (int p = 0; p < 2; ++p) {
            const int h = p * 64 + (t >> 2);
            const int ib = (t & 3) * 4;
            const float4 v = make_float4(tb[(ib + 0) * 132 + h], tb[(ib + 1) * 132 + h],
                                         tb[(ib + 2) * 132 + h], tb[(ib + 3) * 132 + h]);
            *reinterpret_cast<float4*>(&ws_pkcT[(size_t)h * NI + i0 + ib]) = v;
        }
    } else {
        // ---- agg = log(sum spart); pd2 = agg@Wd1+b1; catgy = agg@Wc+bc ----
        const int bd = bx - 612;
        float* a_s = smem;                         // 128
        if (g == 0) {
            float s = 0.f;
            #pragma unroll
            for (int ch = 0; ch < 5; ++ch) s += ws_spart[(bd * 5 + ch) * 128 + c];
            const float av = logf(s);
            a_s[c] = av;
            ws_agg[bd * 128 + c] = av;
        }
        __syncthreads();
        if (g == 0) {
            float acc = b1[c];
            for (int k = 0; k < 128; k += 4) {
                acc = fmaf(a_s[k + 0], W1[(k + 0) * 128 + c], acc);
                acc = fmaf(a_s[k + 1], W1[(k + 1) * 128 + c], acc);
                acc = fmaf(a_s[k + 2], W1[(k + 2) * 128 + c], acc);
                acc = fmaf(a_s[k + 3], W1[(k + 3) * 128 + c], acc);
            }
            ws_pd2[bd * 128 + c] = acc;
        }
        float acc4[4];
        int   col4[4];
        #pragma unroll
        for (int j = 0; j < 4; ++j) {
            const int col = t + j * 256;
            col4[j] = (col < NC) ? col : (NC - 1);
            acc4[j] = bc[col4[j]];
        }
        for (int k = 0; k < 128; ++k) {
            const float av = a_s[k];
            const float* wr = Wc + (size_t)k * NC;
            #pragma unroll
            for (int j = 0; j < 4; ++j) acc4[j] = fmaf(av, wr[col4[j]], acc4[j]);
        }
        #pragma unroll
        for (int j = 0; j < 4; ++j) {
            const int col = t + j * 256;
            if (col < NC) out_cat[bd * NC + col] = acc4[j];
        }
    }
}

// ---------------------------------------------------------------------------
// K3: blocks 0..1023 cand_score (4 rows/thread, prefetched pkcT stream),
// blocks 1024..1823 demand_score (one (b,l) each), blocks 1824..1839 loss.
__global__ __launch_bounds__(256) void k_tail3(
    const float* __restrict__ ws_agg, const float* __restrict__ ws_pd2,
    const float* __restrict__ ws_pk, const float* __restrict__ ws_pkcT,
    const float* __restrict__ w_score, float* __restrict__ out_ds,
    float* __restrict__ out_dsc, float* __restrict__ out_loss)
{
    const int bx = blockIdx.x;
    const int t = threadIdx.x;
    __shared__ __align__(16) float smem[928];
    float* pd_s = smem;            // 512 (cand rows)
    float* ws_s = smem + 512;      // 128
    float* sp   = smem + 640;      // 256 (loss)
    float* aux  = smem + 896;      // normp[16] + wred[4] + red[16]

    if (bx < 1024) {
        // ---- cand_score: bx = b*64 + rh*32 + ichunk; 4 rows/thread ----
        const int ichunk = bx & 31, rh = (bx >> 5) & 1, b = bx >> 6;
        const int r0 = b * 8 + rh * 4;
        const int i = ichunk * 256 + t;
        for (int j = t; j < 512; j += 256) pd_s[j] = ws_pd2[r0 * 128 + j];
        if (t < 128) ws_s[t] = w_score[t];
        __syncthreads();
        float a0 = 0.f, a1 = 0.f, a2 = 0.f, a3 = 0.f;
        const float* __restrict__ pc0 = ws_pkcT + i;
        float4 pv = make_float4(pc0[0], pc0[NI], pc0[2 * NI], pc0[3 * NI]);
        for (int h = 0; h < 128; h += 4) {
            const float4 cur = pv;
            if (h + 4 < 128) {
                const float* __restrict__ pn = ws_pkcT + (size_t)(h + 4) * NI + i;
                pv = make_float4(pn[0], pn[NI], pn[2 * NI], pn[3 * NI]);
            }
            const float4 w4 = *reinterpret_cast<const float4*>(&ws_s[h]);
            const float4 p0 = *reinterpret_cast<const float4*>(&pd_s[h]);
            const float4 p1 = *reinterpret_cast<const float4*>(&pd_s[128 + h]);
            const float4 p2 = *reinterpret_cast<const float4*>(&pd_s[256 + h]);
            const float4 p3 = *reinterpret_cast<const float4*>(&pd_s[384 + h]);
            a0 = fmaf(fmaxf(p0.x + cur.x, 0.f), w4.x, a0);
            a0 = fmaf(fmaxf(p0.y + cur.y, 0.f), w4.y, a0);
            a0 = fmaf(fmaxf(p0.z + cur.z, 0.f), w4.z, a0);
            a0 = fmaf(fmaxf(p0.w + cur.w, 0.f), w4.w, a0);
            a1 = fmaf(fmaxf(p1.x + cur.x, 0.f), w4.x, a1);
            a1 = fmaf(fmaxf(p1.y + cur.y, 0.f), w4.y, a1);
            a1 = fmaf(fmaxf(p1.z + cur.z, 0.f), w4.z, a1);
            a1 = fmaf(fmaxf(p1.w + cur.w, 0.f), w4.w, a1);
            a2 = fmaf(fmaxf(p2.x + cur.x, 0.f), w4.x, a2);
            a2 = fmaf(fmaxf(p2.y + cur.y, 0.f), w4.y, a2);
            a2 = fmaf(fmaxf(p2.z + cur.z, 0.f), w4.z, a2);
            a2 = fmaf(fmaxf(p2.w + cur.w, 0.f), w4.w, a2);
            a3 = fmaf(fmaxf(p3.x + cur.x, 0.f), w4.x, a3);
            a3 = fmaf(fmaxf(p3.y + cur.y, 0.f), w4.y, a3);
            a3 = fmaf(fmaxf(p3.z + cur.z, 0.f), w4.z, a3);
            a3 = fmaf(fmaxf(p3.w + cur.w, 0.f), w4.w, a3);
        }
        out_dsc[(size_t)(r0 + 0) * NI + i] = a0;
        out_dsc[(size_t)(r0 + 1) * NI + i] = a1;
        out_dsc[(size_t)(r0 + 2) * NI + i] = a2;
        out_dsc[(size_t)(r0 + 3) * NI + i] = a3;
    } else if (bx < 1824) {
        // ---- demand_score: one (b,l) per block; group g covers d=g*4..g*4+3 ----
        const int bl = bx - 1024;
        const int b = bl / 50, l = bl % 50;
        const int c = t & 127, g = t >> 7;
        const int w = t >> 6, lane = t & 63;
        float* red = aux;                      // [4][4]
        const float pkv = ws_pk[(size_t)bl * 128 + c];
        const float wv = w_score[c];
        #pragma unroll
        for (int r = 0; r < 4; ++r) {
            const int d = g * 4 + r;
            float v = fmaxf(ws_pd2[(b * 8 + d) * 128 + c] + pkv, 0.f) * wv;
            v += __shfl_down(v, 32); v += __shfl_down(v, 16); v += __shfl_down(v, 8);
            v += __shfl_down(v, 4);  v += __shfl_down(v, 2);  v += __shfl_down(v, 1);
            if (lane == 0) red[w * 4 + r] = v;
        }
        __syncthreads();
        if (t < 8) {
            const int gg = t >> 2, rr = t & 3;
            out_ds[b * 400 + l * 8 + t] = red[(2 * gg) * 4 + rr] + red[(2 * gg + 1) * 4 + rr];
        }
    } else {
        // ---- loss: block per b; loss_b = sum_h S_h^2 - sum_d nsq_d*iv_d^2 ----
        const int b = bx - 1824;
        const int c = t & 127, g = t >> 7;
        const int w = t >> 6, lane = t & 63;
        float* normp = aux;            // [4][4]
        float* wred  = aux + 16;       // [4]
        float a[4];
        #pragma unroll
        for (int r = 0; r < 4; ++r) a[r] = ws_agg[(b * 8 + g * 4 + r) * 128 + c];
        #pragma unroll
        for (int r = 0; r < 4; ++r) {
            float s = a[r] * a[r];
            s += __shfl_down(s, 32); s += __shfl_down(s, 16); s += __shfl_down(s, 8);
            s += __shfl_down(s, 4);  s += __shfl_down(s, 2);  s += __shfl_down(s, 1);
            if (lane == 0) normp[w * 4 + r] = s;
        }
        __syncthreads();
        float Sp = 0.f;
        #pragma unroll
        for (int r = 0; r < 4; ++r) {
            const float nsq = normp[(2 * g) * 4 + r] + normp[(2 * g + 1) * 4 + r];
            const float iv = 1.f / (sqrtf(nsq) + 1e-12f);
            Sp = fmaf(a[r], iv, Sp);
        }
        sp[g * 128 + c] = Sp;
        __syncthreads();
        float p = 0.f;
        if (t < 128) {
            const float S = sp[c] + sp[128 + c];
            p = S * S;
        }
        p += __shfl_down(p, 32); p += __shfl_down(p, 16); p += __shfl_down(p, 8);
        p += __shfl_down(p, 4);  p += __shfl_down(p, 2);  p += __shfl_down(p, 1);
        if (lane == 0) wred[w] = p;
        __syncthreads();
        if (t == 0) {
            float corr = 0.f;
            #pragma unroll
            for (int d = 0; d < 8; ++d) {
                const float nsq = normp[(2 * (d >> 2)) * 4 + (d & 3)] +
                                  normp[(2 * (d >> 2) + 1) * 4 + (d & 3)];
                const float iv = 1.f / (sqrtf(nsq) + 1e-12f);
                corr = fmaf(nsq, iv * iv, corr);
            }
            atomicAdd(out_loss,
                      (wred[0] + wred[1] + wred[2] + wred[3] - corr) * (1.0f / 896.0f));
        }
    }
}

// ---------------------------------------------------------------------------
extern "C" void kernel_launch(void* const* d_in, const int* in_sizes, int n_in,
                              void* d_out, int out_size, void* d_ws, size_t ws_size,
                              hipStream_t stream)
{
    const int*   input     = (const int*)d_in[0];
    const int*   cand      = (const int*)d_in[1];
    const float* emb_table = (const float*)d_in[4];
    const float* Wd        = (const float*)d_in[5];
    const float* Wk        = (const float*)d_in[6];
    const float* bk        = (const float*)d_in[7];
    const float* W1        = (const float*)d_in[8];
    const float* b1        = (const float*)d_in[9];
    const float* w_score   = (const float*)d_in[10];
    const float* Wc        = (const float*)d_in[11];
    const float* bc        = (const float*)d_in[12];

    float* out = (float*)d_out;
    float* out_cat  = out + OFF_CAT;
    float* out_ds   = out + OFF_DS;
    float* out_dsc  = out + OFF_DSC;
    float* out_emb  = out + OFF_EMB;
    float* out_embc = out + OFF_EMBC;
    float* out_loss = out + OFF_LOSS;

    float* ws       = (float*)d_ws;
    float* ws_spart = ws + WS_SPART;
    float* ws_pk    = ws + WS_PK;
    float* ws_pkcT  = ws + WS_PKCT;
    float* ws_wp    = ws + WS_WP;
    float* ws_bp    = ws + WS_BP;
    float* ws_agg   = ws + WS_AGG;
    float* ws_pd2   = ws + WS_PD2;

    k_stage0<<<705, 256, 0, stream>>>(input, emb_table, Wd, Wk, bk, W1,
                                      ws_wp, ws_bp, ws_spart, out_loss);
    k_stage1<<<740, 256, 0, stream>>>(input, cand, emb_table, W1, b1, Wc, bc,
                                      ws_wp, ws_bp, ws_spart,
                                      out_emb, out_embc, out_cat,
                                      ws_pk, ws_pkcT, ws_agg, ws_pd2);
    k_tail3<<<1840, 256, 0, stream>>>(ws_agg, ws_pd2, ws_pk, ws_pkcT, w_score,
                                      out_ds, out_dsc, out_loss);
}